// Round 11
// baseline (158.347 us; speedup 1.0000x reference)
//
#include <hip/hip_runtime.h>
#include <math.h>

#define NN 64      // nodes per graph
#define HH 128     // hidden channels
#define NBB 8      // bessel basis
#define TT 32      // time embedding dim
#define BB 64      // batch
#define NROW (BB * NN)        // 4096 total rows
#define PLANE ((size_t)NROW * HH)   // 524288
#define WR1OFF (8 * 16384)    // Wr1 B-frag slabs in Wpack (2 x 4096)

typedef __attribute__((ext_vector_type(8))) short short8;
typedef __attribute__((ext_vector_type(4))) float f32x4;
typedef __attribute__((ext_vector_type(2))) float f32x2;

__device__ __forceinline__ float silu_f(float x) {
  return x * __builtin_amdgcn_rcpf(1.0f + __expf(-x));
}

// native bf16 convert (RNE) — lowers to v_cvt_pk_bf16_f32 on gfx950
__device__ __forceinline__ unsigned short bf1(float x) {
  __bf16 h = (__bf16)x;
  return *(unsigned short*)&h;
}
__device__ __forceinline__ unsigned bf2(float lo, float hi) {
  return (unsigned)bf1(lo) | ((unsigned)bf1(hi) << 16);
}

// 16-row MFMA GEMM tile: C[2] += sA[16][136] @ B (packed frag order).
__device__ __forceinline__ void gemm16(
    const unsigned short (*sA)[136], const unsigned short* __restrict__ Bp,
    int w, int nlo, int quad, f32x4 C[2]) {
  short8 afr[4];
#pragma unroll
  for (int kt = 0; kt < 4; ++kt)
    afr[kt] = *(const short8*)&sA[nlo][kt * 32 + quad * 8];
#pragma unroll
  for (int nt = 0; nt < 2; ++nt)
#pragma unroll
    for (int kt = 0; kt < 4; ++kt) {
      short8 bfr = *(const short8*)&Bp[((kt * 128 + w * 32 + nt * 16 + nlo) * 4 + quad) * 8];
      C[nt] = __builtin_amdgcn_mfma_f32_16x16x32_bf16(afr[kt], bfr, C[nt], 0, 0, 0);
    }
}

// 8-row variant: A rows 8..15 forced to zero (C rows 8..15 unused).
__device__ __forceinline__ void gemm8(
    const unsigned short (*sA)[136], const unsigned short* __restrict__ Bp,
    int w, int nlo, int quad, f32x4 C[2]) {
  const short8 z8 = {0, 0, 0, 0, 0, 0, 0, 0};
  short8 afr[4];
#pragma unroll
  for (int kt = 0; kt < 4; ++kt)
    afr[kt] = (nlo < 8) ? *(const short8*)&sA[nlo][kt * 32 + quad * 8] : z8;
#pragma unroll
  for (int nt = 0; nt < 2; ++nt)
#pragma unroll
    for (int kt = 0; kt < 4; ++kt) {
      short8 bfr = *(const short8*)&Bp[((kt * 128 + w * 32 + nt * 16 + nlo) * 4 + quad) * 8];
      C[nt] = __builtin_amdgcn_mfma_f32_16x16x32_bf16(afr[kt], bfr, C[nt], 0, 0, 0);
    }
}

// Grid 256. Pack all weights -> bf16 MFMA-B-frag order; blocks<64 init h.
__global__ __launch_bounds__(256) void k_init(
    const float* __restrict__ emb, const int* __restrict__ z,
    const float* __restrict__ gf, const float* __restrict__ Wt,
    const float* __restrict__ Wr1, const float* __restrict__ Wr2,
    const float* __restrict__ Wupd, const float* __restrict__ Wmix,
    const float* __restrict__ Wg1, const float* __restrict__ Wg2,
    float* __restrict__ h, unsigned short* __restrict__ Wpack) {
  __shared__ float tvec[HH];
  __shared__ int sz[NN];
  int b4 = blockIdx.x, tid = threadIdx.x;
#pragma unroll
  for (int ii = 0; ii < 2; ++ii) {
    int idx = b4 * 512 + ii * 256 + tid;    // 0..131071
    int m = idx >> 14;
    int local = idx & 16383;
    float val;
    if (m < 2) val = Wr2[idx];
    else if (m < 4) val = Wupd[idx - 32768];
    else if (m < 6) val = Wmix[idx - 65536];
    else if (m == 6) val = Wg1[local];
    else val = Wg2[local];
    int k = local >> 7, n = local & 127;
    int kt = k >> 5, q = (k >> 3) & 3, j = k & 7;
    Wpack[(idx & ~16383) + (((kt * 128 + n) * 4 + q) * 8) + j] = bf1(val);
  }
  if (tid < 32) {                           // Wr1 zero-padded B-frags
    int e = b4 * 32 + tid;                  // 0..8191
    int l = e >> 12, p = e & 4095;          // p = (n*4+q)*8+j
    int n = p >> 5, q = (p >> 3) & 3, j = p & 7;
    float val = (q == 0) ? Wr1[l * NBB * HH + j * HH + n] : 0.f;
    Wpack[WR1OFF + l * 4096 + p] = bf1(val);
  }
  if (b4 < 64) {
    int b = b4;
    if (tid < NN) sz[tid] = z[b * NN + tid];
    if (tid < HH) {
      float acc = 0.f;
#pragma unroll
      for (int k = 0; k < TT; ++k) acc += gf[b * TT + k] * Wt[k * HH + tid];
      tvec[tid] = acc;
    }
    __syncthreads();
    for (int i = tid; i < NN * HH; i += 256) {
      int n = i >> 7, c = i & 127;
      h[(size_t)b * NN * HH + i] = emb[sz[n] * HH + c] + tvec[c];
    }
  }
}

// One block (256 thr = 4 waves) per (b, receiver-pair). Same structure as R10.
__global__ __launch_bounds__(256) void k_layer(
    const float* __restrict__ pos,
    const float* __restrict__ hA,
    const unsigned short* __restrict__ a0in,   // bf16 plane 0 (l=1 only)
    unsigned short* __restrict__ apout,        // bf16 planes
    const unsigned short* __restrict__ Wpack,
    int l) {
  __shared__ __align__(16) unsigned short sh_S[2][NN][136];   // [0] doubles as a0 tile
  __shared__ __align__(16) unsigned short sh_rbh[2][NN][8];
  __shared__ __align__(16) float sh_u[2][3][NN];

  int blk = blockIdx.x;          // b*32 + rp
  int b = blk >> 5, rp = blk & 31;
  int r0 = rp * 2;
  int tid = threadIdx.x;
  int w = tid >> 6, lane = tid & 63;
  int nlo = lane & 15, quad = lane >> 4;

  // ---- hbv base prefetch from hA (C-reg layout) ----
  f32x4 hbv[4][2];
#pragma unroll
  for (int mt = 0; mt < 4; ++mt)
#pragma unroll
    for (int nt = 0; nt < 2; ++nt)
#pragma unroll
      for (int reg = 0; reg < 4; ++reg)
        hbv[mt][nt][reg] =
            hA[((size_t)b * NN + mt * 16 + quad * 4 + reg) * HH + w * 32 + nt * 16 + nlo];

  // ---- Stage A: geometry + bessel; thread = (ri, ksel, s) ----
  {
    int s = tid & 63;
    int ksel = (tid >> 6) & 1;
    int ri = (tid >> 7) & 1;
    int r = r0 + ri;
    const float* pb = pos + b * NN * 3;
    float dx = pb[r * 3 + 0] - pb[s * 3 + 0];
    float dy = pb[r * 3 + 1] - pb[s * 3 + 1];
    float dz = pb[r * 3 + 2] - pb[s * 3 + 2];
    float rr = sqrtf(dx * dx + dy * dy + dz * dz + 1e-12f);
    float inv = __builtin_amdgcn_rcpf(rr);
    if (ksel == 0) {
      sh_u[ri][0][s] = dx * inv; sh_u[ri][1][s] = dy * inv; sh_u[ri][2][s] = dz * inv;
    }
    const float PI_OVER_5 = 0.628318530717958647692f;
    float fc = (s != r && rr < 5.0f) ? 0.5f * (__cosf(PI_OVER_5 * rr) + 1.0f) : 0.0f;
    float base = PI_OVER_5 * rr;
    float sc = inv * fc;
    int k0 = ksel * 4;
    float v0 = __sinf((float)(k0 + 1) * base) * sc;
    float v1 = __sinf((float)(k0 + 2) * base) * sc;
    float v2 = __sinf((float)(k0 + 3) * base) * sc;
    float v3 = __sinf((float)(k0 + 4) * base) * sc;
    *(unsigned*)&sh_rbh[ri][s][k0]     = bf2(v0, v1);
    *(unsigned*)&sh_rbh[ri][s][k0 + 2] = bf2(v2, v3);
  }
  // ---- l==1: stage a0_l0 tile (bf16) into sh_S[0] ----
  if (l) {
    for (int i = tid; i < NN * 64; i += 256) {
      int s = i >> 6, c2 = (i & 63) * 2;
      *(unsigned*)&sh_S[0][s][c2] =
          *(const unsigned*)&a0in[((size_t)b * NN + s) * HH + c2];
    }
  }
  __syncthreads();   // bar1

  // ---- l==1: hbv += a0_l0 @ Wupd0 via MFMA ----
  if (l) {
    const unsigned short* Bu = Wpack + 2 * 16384;
#pragma unroll
    for (int mt = 0; mt < 4; ++mt) {
      short8 afr[4];
#pragma unroll
      for (int kt = 0; kt < 4; ++kt)
        afr[kt] = *(const short8*)&sh_S[0][mt * 16 + nlo][kt * 32 + quad * 8];
#pragma unroll
      for (int nt = 0; nt < 2; ++nt)
#pragma unroll
        for (int kt = 0; kt < 4; ++kt) {
          short8 bfr = *(const short8*)&Bu[((kt * 128 + w * 32 + nt * 16 + nlo) * 4 + quad) * 8];
          hbv[mt][nt] = __builtin_amdgcn_mfma_f32_16x16x32_bf16(afr[kt], bfr, hbv[mt][nt], 0, 0, 0);
        }
    }
    __syncthreads();   // bar2
  }

  // ---- Stage B: S_ri = silu(rb_ri @ Wr1) via MFMA (K=8 zero-padded) ----
  {
    const unsigned short* Wr1p = Wpack + WR1OFF + l * 4096;
    short8 bw[2];
#pragma unroll
    for (int nt = 0; nt < 2; ++nt)
      bw[nt] = *(const short8*)&Wr1p[((w * 32 + nt * 16 + nlo) * 4 + quad) * 8];
    const short8 zero8 = {0, 0, 0, 0, 0, 0, 0, 0};
#pragma unroll
    for (int ri = 0; ri < 2; ++ri)
#pragma unroll
      for (int mtp = 0; mtp < 2; ++mtp) {
        f32x4 Cs[2][2];
#pragma unroll
        for (int mi = 0; mi < 2; ++mi)
#pragma unroll
          for (int nt = 0; nt < 2; ++nt) Cs[mi][nt] = (f32x4){0.f, 0.f, 0.f, 0.f};
#pragma unroll
        for (int mi = 0; mi < 2; ++mi) {
          int mt = mtp * 2 + mi;
          short8 afr = (quad == 0) ? *(const short8*)&sh_rbh[ri][mt * 16 + nlo][0] : zero8;
#pragma unroll
          for (int nt = 0; nt < 2; ++nt)
            Cs[mi][nt] = __builtin_amdgcn_mfma_f32_16x16x32_bf16(afr, bw[nt], Cs[mi][nt], 0, 0, 0);
        }
#pragma unroll
        for (int mi = 0; mi < 2; ++mi)
#pragma unroll
          for (int nt = 0; nt < 2; ++nt)
#pragma unroll
            for (int reg = 0; reg < 4; ++reg) {
              int s = (mtp * 2 + mi) * 16 + quad * 4 + reg;
              int c = w * 32 + nt * 16 + nlo;
              sh_S[ri][s][c] = bf1(silu_f(Cs[mi][nt][reg]));
            }
      }
  }
  __syncthreads();   // bar3

  // ---- Main GEMM + epilogue, both receivers ----
  const unsigned short* Bbase = Wpack + l * 16384;
  short8 bfr[4][2];
#pragma unroll
  for (int kt = 0; kt < 4; ++kt)
#pragma unroll
    for (int nt = 0; nt < 2; ++nt)
      bfr[kt][nt] = *(const short8*)&Bbase[((kt * 128 + w * 32 + nt * 16 + nlo) * 4 + quad) * 8];

  const float invAvg = 1.0f / 63.0f;
#pragma unroll
  for (int ri = 0; ri < 2; ++ri) {
    float acc0[2] = {0.f, 0.f};
    float a1x[2] = {0.f, 0.f};
    float a1y[2] = {0.f, 0.f};
    float a1z[2] = {0.f, 0.f};
#pragma unroll
    for (int mt = 0; mt < 4; ++mt) {
      short8 afr[4];
      int s_a = mt * 16 + nlo;
#pragma unroll
      for (int kt = 0; kt < 4; ++kt)
        afr[kt] = *(const short8*)&sh_S[ri][s_a][kt * 32 + quad * 8];
      float ux[4], uy[4], uz[4];
#pragma unroll
      for (int reg = 0; reg < 4; ++reg) {
        int s = mt * 16 + quad * 4 + reg;
        ux[reg] = sh_u[ri][0][s]; uy[reg] = sh_u[ri][1][s]; uz[reg] = sh_u[ri][2][s];
      }
#pragma unroll
      for (int nt = 0; nt < 2; ++nt) {
        f32x4 C = {0.f, 0.f, 0.f, 0.f};
#pragma unroll
        for (int kt = 0; kt < 4; ++kt)
          C = __builtin_amdgcn_mfma_f32_16x16x32_bf16(afr[kt], bfr[kt][nt], C, 0, 0, 0);
#pragma unroll
        for (int reg = 0; reg < 4; ++reg) {
          float m0 = C[reg] * hbv[mt][nt][reg];
          acc0[nt] += m0;
          a1x[nt] += m0 * ux[reg];
          a1y[nt] += m0 * uy[reg];
          a1z[nt] += m0 * uz[reg];
        }
      }
    }
#pragma unroll
    for (int nt = 0; nt < 2; ++nt) {
      float q0 = acc0[nt], q1 = a1x[nt], q2 = a1y[nt], q3 = a1z[nt];
      q0 += __shfl_xor(q0, 16); q0 += __shfl_xor(q0, 32);
      q1 += __shfl_xor(q1, 16); q1 += __shfl_xor(q1, 32);
      q2 += __shfl_xor(q2, 16); q2 += __shfl_xor(q2, 32);
      q3 += __shfl_xor(q3, 16); q3 += __shfl_xor(q3, 32);
      if (quad == 0) {
        size_t base = (size_t)(b * NN + r0 + ri) * HH + w * 32 + nt * 16 + nlo;
        apout[(l * 4 + 0) * PLANE + base] = bf1(q0 * invAvg);
        apout[(l * 4 + 1) * PLANE + base] = bf1(q1 * invAvg);
        apout[(l * 4 + 2) * PLANE + base] = bf1(q2 * invAvg);
        apout[(l * 4 + 3) * PLANE + base] = bf1(q3 * invAvg);
      }
    }
  }
}

// Final update + readout, 8 rows/block (grid 512), 10 MFMA GEMMs in-block.
__global__ __launch_bounds__(256) void k_update_ro(
    const unsigned short* __restrict__ apbf, const float* __restrict__ hA,
    const unsigned short* __restrict__ Wpack,
    const float* __restrict__ fs, float* __restrict__ out) {
  __shared__ __align__(16) unsigned short sh_a[8][8][136];   // [0] aliased by q later
  __shared__ __align__(16) unsigned short sh_h[8][136];
  __shared__ float red[4][8][3];
  int tid = threadIdx.x, w = tid >> 6, lane = tid & 63;
  int nlo = lane & 15, quad = lane >> 4;
  int row0 = blockIdx.x * 8;
  for (int i = tid; i < 8 * 8 * 64; i += 256) {
    int p = i >> 9, rr = (i >> 6) & 7, c2 = (i & 63) * 2;
    *(unsigned*)&sh_a[p][rr][c2] =
        *(const unsigned*)&apbf[p * PLANE + (size_t)(row0 + rr) * HH + c2];
  }
  // Ch init from hA (C-reg layout); rows >=8 unused
  f32x4 Ch[2];
#pragma unroll
  for (int nt = 0; nt < 2; ++nt)
#pragma unroll
    for (int reg = 0; reg < 4; ++reg)
      Ch[nt][reg] = (quad < 2)
          ? hA[(size_t)(row0 + quad * 4 + reg) * HH + w * 32 + nt * 16 + nlo] : 0.f;
  __syncthreads();
  gemm8(sh_a[0], Wpack + 2 * 16384, w, nlo, quad, Ch);   // + a0l0@Wupd0
  gemm8(sh_a[4], Wpack + 3 * 16384, w, nlo, quad, Ch);   // + a0l1@Wupd1
  f32x4 Cx[2] = {{0,0,0,0},{0,0,0,0}};
  f32x4 Cy[2] = {{0,0,0,0},{0,0,0,0}};
  f32x4 Cz[2] = {{0,0,0,0},{0,0,0,0}};
  gemm8(sh_a[1], Wpack + 4 * 16384, w, nlo, quad, Cx);
  gemm8(sh_a[5], Wpack + 5 * 16384, w, nlo, quad, Cx);
  gemm8(sh_a[2], Wpack + 4 * 16384, w, nlo, quad, Cy);
  gemm8(sh_a[6], Wpack + 5 * 16384, w, nlo, quad, Cy);
  gemm8(sh_a[3], Wpack + 4 * 16384, w, nlo, quad, Cz);
  gemm8(sh_a[7], Wpack + 5 * 16384, w, nlo, quad, Cz);
  // h -> bf16 LDS for gate GEMM (rows 0..7)
  if (quad < 2) {
#pragma unroll
    for (int nt = 0; nt < 2; ++nt)
#pragma unroll
      for (int reg = 0; reg < 4; ++reg)
        sh_h[quad * 4 + reg][w * 32 + nt * 16 + nlo] = bf1(Ch[nt][reg]);
  }
  __syncthreads();   // sh_h ready; all sh_a reads done -> sh_a[0] free to alias
  unsigned short (*sh_q)[136] = sh_a[0];
  f32x4 Cq[2] = {{0,0,0,0},{0,0,0,0}};
  gemm8(sh_h, Wpack + 6 * 16384, w, nlo, quad, Cq);
  if (quad < 2) {
#pragma unroll
    for (int nt = 0; nt < 2; ++nt)
#pragma unroll
      for (int reg = 0; reg < 4; ++reg)
        sh_q[quad * 4 + reg][w * 32 + nt * 16 + nlo] = bf1(silu_f(Cq[nt][reg]));
  }
  __syncthreads();
  f32x4 Cg[2] = {{0,0,0,0},{0,0,0,0}};
  gemm8(sh_q, Wpack + 7 * 16384, w, nlo, quad, Cg);
  // contraction: per-row sums of g*v over this wave's 32 cols
  float pr[3][4];
#pragma unroll
  for (int d = 0; d < 3; ++d)
#pragma unroll
    for (int reg = 0; reg < 4; ++reg) pr[d][reg] = 0.f;
#pragma unroll
  for (int nt = 0; nt < 2; ++nt)
#pragma unroll
    for (int reg = 0; reg < 4; ++reg) {
      float gv = Cg[nt][reg];
      pr[0][reg] += gv * Cx[nt][reg];
      pr[1][reg] += gv * Cy[nt][reg];
      pr[2][reg] += gv * Cz[nt][reg];
    }
#pragma unroll
  for (int off = 1; off < 16; off <<= 1)
#pragma unroll
    for (int d = 0; d < 3; ++d)
#pragma unroll
      for (int reg = 0; reg < 4; ++reg)
        pr[d][reg] += __shfl_xor(pr[d][reg], off);
  if (nlo == 0 && quad < 2) {
#pragma unroll
    for (int d = 0; d < 3; ++d)
#pragma unroll
      for (int reg = 0; reg < 4; ++reg)
        red[w][quad * 4 + reg][d] = pr[d][reg];
  }
  __syncthreads();
  if (tid < 24) {
    int row = tid / 3, d = tid % 3;
    float s = red[0][row][d] + red[1][row][d] + red[2][row][d] + red[3][row][d];
    out[(size_t)(row0 + row) * 3 + d] = s * fs[0];
  }
}

extern "C" void kernel_launch(void* const* d_in, const int* in_sizes, int n_in,
                              void* d_out, int out_size, void* d_ws, size_t ws_size,
                              hipStream_t stream) {
  const float* pos  = (const float*)d_in[0];
  const int*   z    = (const int*)d_in[1];
  const float* gf   = (const float*)d_in[2];
  const float* emb  = (const float*)d_in[3];
  const float* Wt   = (const float*)d_in[4];
  const float* Wr1  = (const float*)d_in[5];
  const float* Wr2  = (const float*)d_in[6];
  const float* Wupd = (const float*)d_in[7];
  const float* Wmix = (const float*)d_in[8];
  const float* Wg1  = (const float*)d_in[9];
  const float* Wg2  = (const float*)d_in[10];
  const float* fs   = (const float*)d_in[11];
  float* out = (float*)d_out;

  float* ws = (float*)d_ws;
  float* hA = ws;                                         // 2 MB
  unsigned short* apbf = (unsigned short*)(ws + PLANE);   // 8 bf16 planes = 8 MB
  unsigned short* Wpack = (unsigned short*)(ws + 5 * PLANE);  // 272 KB

  k_init<<<dim3(256), dim3(256), 0, stream>>>(emb, z, gf, Wt, Wr1, Wr2, Wupd,
                                              Wmix, Wg1, Wg2, hA, Wpack);
  k_layer<<<dim3(BB * 32), dim3(256), 0, stream>>>(pos, hA, apbf, apbf, Wpack, 0);
  k_layer<<<dim3(BB * 32), dim3(256), 0, stream>>>(pos, hA, apbf, apbf, Wpack, 1);
  k_update_ro<<<dim3(512), dim3(256), 0, stream>>>(apbf, hA, Wpack, fs, out);
}

// Round 12
// 158.010 us; speedup vs baseline: 1.0021x; 1.0021x over previous
//
#include <hip/hip_runtime.h>
#include <math.h>

#define NN 64      // nodes per graph
#define HH 128     // hidden channels
#define NBB 8      // bessel basis
#define TT 32      // time embedding dim
#define BB 64      // batch
#define NROW (BB * NN)        // 4096 total rows
#define PLANE ((size_t)NROW * HH)   // 524288
#define WR1OFF (8 * 16384)    // Wr1 B-frag slabs in Wpack (2 x 4096)

typedef __attribute__((ext_vector_type(8))) short short8;
typedef __attribute__((ext_vector_type(4))) float f32x4;
typedef __attribute__((ext_vector_type(2))) float f32x2;

__device__ __forceinline__ float silu_f(float x) {
  return x * __builtin_amdgcn_rcpf(1.0f + __expf(-x));
}

__device__ __forceinline__ unsigned short bf1(float x) {
  __bf16 h = (__bf16)x;
  return *(unsigned short*)&h;
}
__device__ __forceinline__ unsigned bf2(float lo, float hi) {
  return (unsigned)bf1(lo) | ((unsigned)bf1(hi) << 16);
}

// 8-row MFMA GEMM tile: A rows 8..15 zero. C map: row=quad*4+reg (<8), col=w*32+nt*16+nlo.
__device__ __forceinline__ void gemm8(
    const unsigned short (*sA)[136], const unsigned short* __restrict__ Bp,
    int w, int nlo, int quad, f32x4 C[2]) {
  const short8 z8 = {0, 0, 0, 0, 0, 0, 0, 0};
  short8 afr[4];
#pragma unroll
  for (int kt = 0; kt < 4; ++kt)
    afr[kt] = (nlo < 8) ? *(const short8*)&sA[nlo][kt * 32 + quad * 8] : z8;
#pragma unroll
  for (int nt = 0; nt < 2; ++nt)
#pragma unroll
    for (int kt = 0; kt < 4; ++kt) {
      short8 bfr = *(const short8*)&Bp[((kt * 128 + w * 32 + nt * 16 + nlo) * 4 + quad) * 8];
      C[nt] = __builtin_amdgcn_mfma_f32_16x16x32_bf16(afr[kt], bfr, C[nt], 0, 0, 0);
    }
}

// Grid 256. Pack all weights -> bf16 MFMA-B-frag order; blocks<64 init h.
__global__ __launch_bounds__(256) void k_init(
    const float* __restrict__ emb, const int* __restrict__ z,
    const float* __restrict__ gf, const float* __restrict__ Wt,
    const float* __restrict__ Wr1, const float* __restrict__ Wr2,
    const float* __restrict__ Wupd, const float* __restrict__ Wmix,
    const float* __restrict__ Wg1, const float* __restrict__ Wg2,
    float* __restrict__ h, unsigned short* __restrict__ Wpack) {
  __shared__ float tvec[HH];
  __shared__ int sz[NN];
  int b4 = blockIdx.x, tid = threadIdx.x;
#pragma unroll
  for (int ii = 0; ii < 2; ++ii) {
    int idx = b4 * 512 + ii * 256 + tid;    // 0..131071
    int m = idx >> 14;
    int local = idx & 16383;
    float val;
    if (m < 2) val = Wr2[idx];
    else if (m < 4) val = Wupd[idx - 32768];
    else if (m < 6) val = Wmix[idx - 65536];
    else if (m == 6) val = Wg1[local];
    else val = Wg2[local];
    int k = local >> 7, n = local & 127;
    int kt = k >> 5, q = (k >> 3) & 3, j = k & 7;
    Wpack[(idx & ~16383) + (((kt * 128 + n) * 4 + q) * 8) + j] = bf1(val);
  }
  if (tid < 32) {                           // Wr1 zero-padded B-frags
    int e = b4 * 32 + tid;                  // 0..8191
    int l = e >> 12, p = e & 4095;          // p = (n*4+q)*8+j
    int n = p >> 5, q = (p >> 3) & 3, j = p & 7;
    float val = (q == 0) ? Wr1[l * NBB * HH + j * HH + n] : 0.f;
    Wpack[WR1OFF + l * 4096 + p] = bf1(val);
  }
  if (b4 < 64) {
    int b = b4;
    if (tid < NN) sz[tid] = z[b * NN + tid];
    if (tid < HH) {
      float acc = 0.f;
#pragma unroll
      for (int k = 0; k < TT; ++k) acc += gf[b * TT + k] * Wt[k * HH + tid];
      tvec[tid] = acc;
    }
    __syncthreads();
    for (int i = tid; i < NN * HH; i += 256) {
      int n = i >> 7, c = i & 127;
      h[(size_t)b * NN * HH + i] = emb[sz[n] * HH + c] + tvec[c];
    }
  }
}

// One block (256 thr = 4 waves) per (b, receiver-pair {2rp, 2rp+1}).
// SINGLE S buffer: the two receivers share it sequentially (StageB -> GEMM
// -> bar -> StageB -> GEMM). LDS 20.9 KB -> ~3 blocks/CU (vs 38.4 KB -> 1).
__global__ __launch_bounds__(256) void k_layer(
    const float* __restrict__ pos,
    const float* __restrict__ hA,
    const unsigned short* __restrict__ a0in,   // bf16 plane 0 (l=1 only)
    unsigned short* __restrict__ apout,        // bf16 planes
    const unsigned short* __restrict__ Wpack,
    int l) {
  __shared__ __align__(16) unsigned short sh_S[NN][136];    // 17408 B (also a0 tile)
  __shared__ __align__(16) unsigned short sh_rbh[2][NN][8]; // 2048 B
  __shared__ __align__(16) float sh_u[2][3][NN];            // 1536 B

  int blk = blockIdx.x;          // b*32 + rp
  int b = blk >> 5, rp = blk & 31;
  int r0 = rp * 2;
  int tid = threadIdx.x;
  int w = tid >> 6, lane = tid & 63;
  int nlo = lane & 15, quad = lane >> 4;

  // ---- hbv base prefetch from hA (C-reg layout) ----
  f32x4 hbv[4][2];
#pragma unroll
  for (int mt = 0; mt < 4; ++mt)
#pragma unroll
    for (int nt = 0; nt < 2; ++nt)
#pragma unroll
      for (int reg = 0; reg < 4; ++reg)
        hbv[mt][nt][reg] =
            hA[((size_t)b * NN + mt * 16 + quad * 4 + reg) * HH + w * 32 + nt * 16 + nlo];

  // ---- Stage A: geometry + bessel; thread = (ri, ksel, s) ----
  {
    int s = tid & 63;
    int ksel = (tid >> 6) & 1;
    int ri = (tid >> 7) & 1;
    int r = r0 + ri;
    const float* pb = pos + b * NN * 3;
    float dx = pb[r * 3 + 0] - pb[s * 3 + 0];
    float dy = pb[r * 3 + 1] - pb[s * 3 + 1];
    float dz = pb[r * 3 + 2] - pb[s * 3 + 2];
    float rr = sqrtf(dx * dx + dy * dy + dz * dz + 1e-12f);
    float inv = __builtin_amdgcn_rcpf(rr);
    if (ksel == 0) {
      sh_u[ri][0][s] = dx * inv; sh_u[ri][1][s] = dy * inv; sh_u[ri][2][s] = dz * inv;
    }
    const float PI_OVER_5 = 0.628318530717958647692f;
    float fc = (s != r && rr < 5.0f) ? 0.5f * (__cosf(PI_OVER_5 * rr) + 1.0f) : 0.0f;
    float base = PI_OVER_5 * rr;
    float sc = inv * fc;
    int k0 = ksel * 4;
    float v0 = __sinf((float)(k0 + 1) * base) * sc;
    float v1 = __sinf((float)(k0 + 2) * base) * sc;
    float v2 = __sinf((float)(k0 + 3) * base) * sc;
    float v3 = __sinf((float)(k0 + 4) * base) * sc;
    *(unsigned*)&sh_rbh[ri][s][k0]     = bf2(v0, v1);
    *(unsigned*)&sh_rbh[ri][s][k0 + 2] = bf2(v2, v3);
  }
  // ---- l==1: stage a0_l0 tile (bf16) into sh_S ----
  if (l) {
    for (int i = tid; i < NN * 64; i += 256) {
      int s = i >> 6, c2 = (i & 63) * 2;
      *(unsigned*)&sh_S[s][c2] =
          *(const unsigned*)&a0in[((size_t)b * NN + s) * HH + c2];
    }
  }
  __syncthreads();   // bar1: rbh/u (and a0 tile) ready

  // ---- l==1: hbv += a0_l0 @ Wupd0 via MFMA ----
  if (l) {
    const unsigned short* Bu = Wpack + 2 * 16384;
#pragma unroll
    for (int mt = 0; mt < 4; ++mt) {
      short8 afr[4];
#pragma unroll
      for (int kt = 0; kt < 4; ++kt)
        afr[kt] = *(const short8*)&sh_S[mt * 16 + nlo][kt * 32 + quad * 8];
#pragma unroll
      for (int nt = 0; nt < 2; ++nt)
#pragma unroll
        for (int kt = 0; kt < 4; ++kt) {
          short8 bfr = *(const short8*)&Bu[((kt * 128 + w * 32 + nt * 16 + nlo) * 4 + quad) * 8];
          hbv[mt][nt] = __builtin_amdgcn_mfma_f32_16x16x32_bf16(afr[kt], bfr, hbv[mt][nt], 0, 0, 0);
        }
    }
    __syncthreads();   // bar2: sh_S reads done before Stage B overwrites
  }

  // ---- hoisted fragment loads (L2-hot, shared by both receivers) ----
  const unsigned short* Wr1p = Wpack + WR1OFF + l * 4096;
  short8 bw[2];
#pragma unroll
  for (int nt = 0; nt < 2; ++nt)
    bw[nt] = *(const short8*)&Wr1p[((w * 32 + nt * 16 + nlo) * 4 + quad) * 8];
  const unsigned short* Bbase = Wpack + l * 16384;
  short8 bfr[4][2];
#pragma unroll
  for (int kt = 0; kt < 4; ++kt)
#pragma unroll
    for (int nt = 0; nt < 2; ++nt)
      bfr[kt][nt] = *(const short8*)&Bbase[((kt * 128 + w * 32 + nt * 16 + nlo) * 4 + quad) * 8];

  const short8 zero8 = {0, 0, 0, 0, 0, 0, 0, 0};
  const float invAvg = 1.0f / 63.0f;

#pragma unroll
  for (int ri = 0; ri < 2; ++ri) {
    // ---- Stage B: S_ri = silu(rb_ri @ Wr1) via MFMA -> sh_S ----
#pragma unroll
    for (int mtp = 0; mtp < 2; ++mtp) {
      f32x4 Cs[2][2];
#pragma unroll
      for (int mi = 0; mi < 2; ++mi)
#pragma unroll
        for (int nt = 0; nt < 2; ++nt) Cs[mi][nt] = (f32x4){0.f, 0.f, 0.f, 0.f};
#pragma unroll
      for (int mi = 0; mi < 2; ++mi) {
        int mt = mtp * 2 + mi;
        short8 afr = (quad == 0) ? *(const short8*)&sh_rbh[ri][mt * 16 + nlo][0] : zero8;
#pragma unroll
        for (int nt = 0; nt < 2; ++nt)
          Cs[mi][nt] = __builtin_amdgcn_mfma_f32_16x16x32_bf16(afr, bw[nt], Cs[mi][nt], 0, 0, 0);
      }
#pragma unroll
      for (int mi = 0; mi < 2; ++mi)
#pragma unroll
        for (int nt = 0; nt < 2; ++nt)
#pragma unroll
          for (int reg = 0; reg < 4; ++reg) {
            int s = (mtp * 2 + mi) * 16 + quad * 4 + reg;
            int c = w * 32 + nt * 16 + nlo;
            sh_S[s][c] = bf1(silu_f(Cs[mi][nt][reg]));
          }
    }
    __syncthreads();   // S_ri ready

    // ---- Main GEMM + epilogue for this receiver ----
    float acc0[2] = {0.f, 0.f};
    float a1x[2] = {0.f, 0.f};
    float a1y[2] = {0.f, 0.f};
    float a1z[2] = {0.f, 0.f};
#pragma unroll
    for (int mt = 0; mt < 4; ++mt) {
      short8 afr[4];
      int s_a = mt * 16 + nlo;
#pragma unroll
      for (int kt = 0; kt < 4; ++kt)
        afr[kt] = *(const short8*)&sh_S[s_a][kt * 32 + quad * 8];
      float ux[4], uy[4], uz[4];
#pragma unroll
      for (int reg = 0; reg < 4; ++reg) {
        int s = mt * 16 + quad * 4 + reg;
        ux[reg] = sh_u[ri][0][s]; uy[reg] = sh_u[ri][1][s]; uz[reg] = sh_u[ri][2][s];
      }
#pragma unroll
      for (int nt = 0; nt < 2; ++nt) {
        f32x4 C = {0.f, 0.f, 0.f, 0.f};
#pragma unroll
        for (int kt = 0; kt < 4; ++kt)
          C = __builtin_amdgcn_mfma_f32_16x16x32_bf16(afr[kt], bfr[kt][nt], C, 0, 0, 0);
#pragma unroll
        for (int reg = 0; reg < 4; ++reg) {
          float m0 = C[reg] * hbv[mt][nt][reg];
          acc0[nt] += m0;
          a1x[nt] += m0 * ux[reg];
          a1y[nt] += m0 * uy[reg];
          a1z[nt] += m0 * uz[reg];
        }
      }
    }
#pragma unroll
    for (int nt = 0; nt < 2; ++nt) {
      float q0 = acc0[nt], q1 = a1x[nt], q2 = a1y[nt], q3 = a1z[nt];
      q0 += __shfl_xor(q0, 16); q0 += __shfl_xor(q0, 32);
      q1 += __shfl_xor(q1, 16); q1 += __shfl_xor(q1, 32);
      q2 += __shfl_xor(q2, 16); q2 += __shfl_xor(q2, 32);
      q3 += __shfl_xor(q3, 16); q3 += __shfl_xor(q3, 32);
      if (quad == 0) {
        size_t base = (size_t)(b * NN + r0 + ri) * HH + w * 32 + nt * 16 + nlo;
        apout[(l * 4 + 0) * PLANE + base] = bf1(q0 * invAvg);
        apout[(l * 4 + 1) * PLANE + base] = bf1(q1 * invAvg);
        apout[(l * 4 + 2) * PLANE + base] = bf1(q2 * invAvg);
        apout[(l * 4 + 3) * PLANE + base] = bf1(q3 * invAvg);
      }
    }
    if (ri == 0) __syncthreads();   // sh_S reads done before ri=1 overwrite
  }
}

// Final update + readout, 8 rows/block (grid 512), 10 MFMA GEMMs in-block.
__global__ __launch_bounds__(256) void k_update_ro(
    const unsigned short* __restrict__ apbf, const float* __restrict__ hA,
    const unsigned short* __restrict__ Wpack,
    const float* __restrict__ fs, float* __restrict__ out) {
  __shared__ __align__(16) unsigned short sh_a[8][8][136];   // [0] aliased by q later
  __shared__ __align__(16) unsigned short sh_h[8][136];
  __shared__ float red[4][8][3];
  int tid = threadIdx.x, w = tid >> 6, lane = tid & 63;
  int nlo = lane & 15, quad = lane >> 4;
  int row0 = blockIdx.x * 8;
  for (int i = tid; i < 8 * 8 * 64; i += 256) {
    int p = i >> 9, rr = (i >> 6) & 7, c2 = (i & 63) * 2;
    *(unsigned*)&sh_a[p][rr][c2] =
        *(const unsigned*)&apbf[p * PLANE + (size_t)(row0 + rr) * HH + c2];
  }
  f32x4 Ch[2];
#pragma unroll
  for (int nt = 0; nt < 2; ++nt)
#pragma unroll
    for (int reg = 0; reg < 4; ++reg)
      Ch[nt][reg] = (quad < 2)
          ? hA[(size_t)(row0 + quad * 4 + reg) * HH + w * 32 + nt * 16 + nlo] : 0.f;
  __syncthreads();
  gemm8(sh_a[0], Wpack + 2 * 16384, w, nlo, quad, Ch);   // + a0l0@Wupd0
  gemm8(sh_a[4], Wpack + 3 * 16384, w, nlo, quad, Ch);   // + a0l1@Wupd1
  f32x4 Cx[2] = {{0,0,0,0},{0,0,0,0}};
  f32x4 Cy[2] = {{0,0,0,0},{0,0,0,0}};
  f32x4 Cz[2] = {{0,0,0,0},{0,0,0,0}};
  gemm8(sh_a[1], Wpack + 4 * 16384, w, nlo, quad, Cx);
  gemm8(sh_a[5], Wpack + 5 * 16384, w, nlo, quad, Cx);
  gemm8(sh_a[2], Wpack + 4 * 16384, w, nlo, quad, Cy);
  gemm8(sh_a[6], Wpack + 5 * 16384, w, nlo, quad, Cy);
  gemm8(sh_a[3], Wpack + 4 * 16384, w, nlo, quad, Cz);
  gemm8(sh_a[7], Wpack + 5 * 16384, w, nlo, quad, Cz);
  if (quad < 2) {
#pragma unroll
    for (int nt = 0; nt < 2; ++nt)
#pragma unroll
      for (int reg = 0; reg < 4; ++reg)
        sh_h[quad * 4 + reg][w * 32 + nt * 16 + nlo] = bf1(Ch[nt][reg]);
  }
  __syncthreads();   // sh_h ready; sh_a reads done -> sh_a[0] free to alias
  unsigned short (*sh_q)[136] = sh_a[0];
  f32x4 Cq[2] = {{0,0,0,0},{0,0,0,0}};
  gemm8(sh_h, Wpack + 6 * 16384, w, nlo, quad, Cq);
  if (quad < 2) {
#pragma unroll
    for (int nt = 0; nt < 2; ++nt)
#pragma unroll
      for (int reg = 0; reg < 4; ++reg)
        sh_q[quad * 4 + reg][w * 32 + nt * 16 + nlo] = bf1(silu_f(Cq[nt][reg]));
  }
  __syncthreads();
  f32x4 Cg[2] = {{0,0,0,0},{0,0,0,0}};
  gemm8(sh_q, Wpack + 7 * 16384, w, nlo, quad, Cg);
  float pr[3][4];
#pragma unroll
  for (int d = 0; d < 3; ++d)
#pragma unroll
    for (int reg = 0; reg < 4; ++reg) pr[d][reg] = 0.f;
#pragma unroll
  for (int nt = 0; nt < 2; ++nt)
#pragma unroll
    for (int reg = 0; reg < 4; ++reg) {
      float gv = Cg[nt][reg];
      pr[0][reg] += gv * Cx[nt][reg];
      pr[1][reg] += gv * Cy[nt][reg];
      pr[2][reg] += gv * Cz[nt][reg];
    }
#pragma unroll
  for (int off = 1; off < 16; off <<= 1)
#pragma unroll
    for (int d = 0; d < 3; ++d)
#pragma unroll
      for (int reg = 0; reg < 4; ++reg)
        pr[d][reg] += __shfl_xor(pr[d][reg], off);
  if (nlo == 0 && quad < 2) {
#pragma unroll
    for (int d = 0; d < 3; ++d)
#pragma unroll
      for (int reg = 0; reg < 4; ++reg)
        red[w][quad * 4 + reg][d] = pr[d][reg];
  }
  __syncthreads();
  if (tid < 24) {
    int row = tid / 3, d = tid % 3;
    float s = red[0][row][d] + red[1][row][d] + red[2][row][d] + red[3][row][d];
    out[(size_t)(row0 + row) * 3 + d] = s * fs[0];
  }
}

extern "C" void kernel_launch(void* const* d_in, const int* in_sizes, int n_in,
                              void* d_out, int out_size, void* d_ws, size_t ws_size,
                              hipStream_t stream) {
  const float* pos  = (const float*)d_in[0];
  const int*   z    = (const int*)d_in[1];
  const float* gf   = (const float*)d_in[2];
  const float* emb  = (const float*)d_in[3];
  const float* Wt   = (const float*)d_in[4];
  const float* Wr1  = (const float*)d_in[5];
  const float* Wr2  = (const float*)d_in[6];
  const float* Wupd = (const float*)d_in[7];
  const float* Wmix = (const float*)d_in[8];
  const float* Wg1  = (const float*)d_in[9];
  const float* Wg2  = (const float*)d_in[10];
  const float* fs   = (const float*)d_in[11];
  float* out = (float*)d_out;

  float* ws = (float*)d_ws;
  float* hA = ws;                                         // 2 MB
  unsigned short* apbf = (unsigned short*)(ws + PLANE);   // 8 bf16 planes = 8 MB
  unsigned short* Wpack = (unsigned short*)(ws + 5 * PLANE);  // 272 KB

  k_init<<<dim3(256), dim3(256), 0, stream>>>(emb, z, gf, Wt, Wr1, Wr2, Wupd,
                                              Wmix, Wg1, Wg2, hA, Wpack);
  k_layer<<<dim3(BB * 32), dim3(256), 0, stream>>>(pos, hA, apbf, apbf, Wpack, 0);
  k_layer<<<dim3(BB * 32), dim3(256), 0, stream>>>(pos, hA, apbf, apbf, Wpack, 1);
  k_update_ro<<<dim3(512), dim3(256), 0, stream>>>(apbf, hA, Wpack, fs, out);
}

// Round 13
// 152.768 us; speedup vs baseline: 1.0365x; 1.0343x over previous
//
#include <hip/hip_runtime.h>
#include <math.h>

#define NN 64      // nodes per graph
#define HH 128     // hidden channels
#define NBB 8      // bessel basis
#define TT 32      // time embedding dim
#define BB 64      // batch
#define NROW (BB * NN)        // 4096 total rows
#define PLANE ((size_t)NROW * HH)   // 524288
#define WR1OFF (8 * 16384)    // Wr1 B-frag slabs in Wpack (2 x 4096)

typedef __attribute__((ext_vector_type(8))) short short8;
typedef __attribute__((ext_vector_type(4))) float f32x4;
typedef __attribute__((ext_vector_type(2))) float f32x2;
typedef __attribute__((ext_vector_type(2))) unsigned int u32x2;

__device__ __forceinline__ float silu_f(float x) {
  return x * __builtin_amdgcn_rcpf(1.0f + __expf(-x));
}

__device__ __forceinline__ unsigned short bf1(float x) {
  __bf16 h = (__bf16)x;
  return *(unsigned short*)&h;
}
__device__ __forceinline__ unsigned bf2(float lo, float hi) {
  return (unsigned)bf1(lo) | ((unsigned)bf1(hi) << 16);
}

// 8-row MFMA GEMM tile: A rows 8..15 zero. C map: row=quad*4+reg (<8), col=w*32+nt*16+nlo.
__device__ __forceinline__ void gemm8(
    const unsigned short (*sA)[136], const unsigned short* __restrict__ Bp,
    int w, int nlo, int quad, f32x4 C[2]) {
  const short8 z8 = {0, 0, 0, 0, 0, 0, 0, 0};
  short8 afr[4];
#pragma unroll
  for (int kt = 0; kt < 4; ++kt)
    afr[kt] = (nlo < 8) ? *(const short8*)&sA[nlo][kt * 32 + quad * 8] : z8;
#pragma unroll
  for (int nt = 0; nt < 2; ++nt)
#pragma unroll
    for (int kt = 0; kt < 4; ++kt) {
      short8 bfr = *(const short8*)&Bp[((kt * 128 + w * 32 + nt * 16 + nlo) * 4 + quad) * 8];
      C[nt] = __builtin_amdgcn_mfma_f32_16x16x32_bf16(afr[kt], bfr, C[nt], 0, 0, 0);
    }
}

// Grid 256. Pack all weights -> bf16 MFMA-B-frag order; blocks<64 init h.
__global__ __launch_bounds__(256) void k_init(
    const float* __restrict__ emb, const int* __restrict__ z,
    const float* __restrict__ gf, const float* __restrict__ Wt,
    const float* __restrict__ Wr1, const float* __restrict__ Wr2,
    const float* __restrict__ Wupd, const float* __restrict__ Wmix,
    const float* __restrict__ Wg1, const float* __restrict__ Wg2,
    float* __restrict__ h, unsigned short* __restrict__ Wpack) {
  __shared__ float tvec[HH];
  __shared__ int sz[NN];
  int b4 = blockIdx.x, tid = threadIdx.x;
#pragma unroll
  for (int ii = 0; ii < 2; ++ii) {
    int idx = b4 * 512 + ii * 256 + tid;    // 0..131071
    int m = idx >> 14;
    int local = idx & 16383;
    float val;
    if (m < 2) val = Wr2[idx];
    else if (m < 4) val = Wupd[idx - 32768];
    else if (m < 6) val = Wmix[idx - 65536];
    else if (m == 6) val = Wg1[local];
    else val = Wg2[local];
    int k = local >> 7, n = local & 127;
    int kt = k >> 5, q = (k >> 3) & 3, j = k & 7;
    Wpack[(idx & ~16383) + (((kt * 128 + n) * 4 + q) * 8) + j] = bf1(val);
  }
  if (tid < 32) {                           // Wr1 zero-padded B-frags
    int e = b4 * 32 + tid;                  // 0..8191
    int l = e >> 12, p = e & 4095;          // p = (n*4+q)*8+j
    int n = p >> 5, q = (p >> 3) & 3, j = p & 7;
    float val = (q == 0) ? Wr1[l * NBB * HH + j * HH + n] : 0.f;
    Wpack[WR1OFF + l * 4096 + p] = bf1(val);
  }
  if (b4 < 64) {
    int b = b4;
    if (tid < NN) sz[tid] = z[b * NN + tid];
    if (tid < HH) {
      float acc = 0.f;
#pragma unroll
      for (int k = 0; k < TT; ++k) acc += gf[b * TT + k] * Wt[k * HH + tid];
      tvec[tid] = acc;
    }
    __syncthreads();
    for (int i = tid; i < NN * HH; i += 256) {
      int n = i >> 7, c = i & 127;
      h[(size_t)b * NN * HH + i] = emb[sz[n] * HH + c] + tvec[c];
    }
  }
}

// One block (256 thr = 4 waves) per (b, receiver-pair {2rp, 2rp+1}).
// Epilogue is now MFMA: M0 = (S@Wr2)*h -> per-wave transposed LDS tile,
// then [a0;a1x;a1y;a1z] = U @ M0 with U rows = {1,ux,uy,uz}/63 (bf16).
__global__ __launch_bounds__(256) void k_layer(
    const float* __restrict__ pos,
    const float* __restrict__ hA,
    const unsigned short* __restrict__ a0in,   // bf16 plane 0 (l=1 only)
    unsigned short* __restrict__ apout,        // bf16 planes
    const unsigned short* __restrict__ Wpack,
    int l) {
  __shared__ __align__(16) unsigned short sh_S[NN][136];     // 17408 B (also a0 tile)
  __shared__ __align__(16) unsigned short sh_M0T[4][32][72]; // 18432 B, per-wave [c][s]
  __shared__ __align__(16) unsigned short sh_rbh[2][NN][8];  // 2048 B
  __shared__ __align__(16) unsigned short sh_ub[2][4][NN];   // 1024 B: U rows (bf16)

  int blk = blockIdx.x;          // b*32 + rp
  int b = blk >> 5, rp = blk & 31;
  int r0 = rp * 2;
  int tid = threadIdx.x;
  int w = tid >> 6, lane = tid & 63;
  int nlo = lane & 15, quad = lane >> 4;

  // ---- hbv base prefetch from hA (C-reg layout) ----
  f32x4 hbv[4][2];
#pragma unroll
  for (int mt = 0; mt < 4; ++mt)
#pragma unroll
    for (int nt = 0; nt < 2; ++nt)
#pragma unroll
      for (int reg = 0; reg < 4; ++reg)
        hbv[mt][nt][reg] =
            hA[((size_t)b * NN + mt * 16 + quad * 4 + reg) * HH + w * 32 + nt * 16 + nlo];

  // ---- Stage A: geometry + bessel; thread = (ri, ksel, s) ----
  {
    int s = tid & 63;
    int ksel = (tid >> 6) & 1;
    int ri = (tid >> 7) & 1;
    int r = r0 + ri;
    const float* pb = pos + b * NN * 3;
    float dx = pb[r * 3 + 0] - pb[s * 3 + 0];
    float dy = pb[r * 3 + 1] - pb[s * 3 + 1];
    float dz = pb[r * 3 + 2] - pb[s * 3 + 2];
    float rr = sqrtf(dx * dx + dy * dy + dz * dz + 1e-12f);
    float inv = __builtin_amdgcn_rcpf(rr);
    const float invAvg = 1.0f / 63.0f;
    if (ksel == 0) {
      float ia = inv * invAvg;
      sh_ub[ri][1][s] = bf1(dx * ia);
      sh_ub[ri][2][s] = bf1(dy * ia);
      sh_ub[ri][3][s] = bf1(dz * ia);
    } else {
      sh_ub[ri][0][s] = bf1(invAvg);
    }
    const float PI_OVER_5 = 0.628318530717958647692f;
    float fc = (s != r && rr < 5.0f) ? 0.5f * (__cosf(PI_OVER_5 * rr) + 1.0f) : 0.0f;
    float base = PI_OVER_5 * rr;
    float sc = inv * fc;
    int k0 = ksel * 4;
    float v0 = __sinf((float)(k0 + 1) * base) * sc;
    float v1 = __sinf((float)(k0 + 2) * base) * sc;
    float v2 = __sinf((float)(k0 + 3) * base) * sc;
    float v3 = __sinf((float)(k0 + 4) * base) * sc;
    *(unsigned*)&sh_rbh[ri][s][k0]     = bf2(v0, v1);
    *(unsigned*)&sh_rbh[ri][s][k0 + 2] = bf2(v2, v3);
  }
  // ---- l==1: stage a0_l0 tile (bf16) into sh_S ----
  if (l) {
    for (int i = tid; i < NN * 64; i += 256) {
      int s = i >> 6, c2 = (i & 63) * 2;
      *(unsigned*)&sh_S[s][c2] =
          *(const unsigned*)&a0in[((size_t)b * NN + s) * HH + c2];
    }
  }
  __syncthreads();   // bar1: rbh/ub (and a0 tile) ready

  // ---- l==1: hbv += a0_l0 @ Wupd0 via MFMA ----
  if (l) {
    const unsigned short* Bu = Wpack + 2 * 16384;
#pragma unroll
    for (int mt = 0; mt < 4; ++mt) {
      short8 afr[4];
#pragma unroll
      for (int kt = 0; kt < 4; ++kt)
        afr[kt] = *(const short8*)&sh_S[mt * 16 + nlo][kt * 32 + quad * 8];
#pragma unroll
      for (int nt = 0; nt < 2; ++nt)
#pragma unroll
        for (int kt = 0; kt < 4; ++kt) {
          short8 bfr = *(const short8*)&Bu[((kt * 128 + w * 32 + nt * 16 + nlo) * 4 + quad) * 8];
          hbv[mt][nt] = __builtin_amdgcn_mfma_f32_16x16x32_bf16(afr[kt], bfr, hbv[mt][nt], 0, 0, 0);
        }
    }
    __syncthreads();   // bar2: sh_S reads done before Stage B overwrites
  }

  // ---- hoisted fragment loads (L2-hot, shared by both receivers) ----
  const unsigned short* Wr1p = Wpack + WR1OFF + l * 4096;
  short8 bw[2];
#pragma unroll
  for (int nt = 0; nt < 2; ++nt)
    bw[nt] = *(const short8*)&Wr1p[((w * 32 + nt * 16 + nlo) * 4 + quad) * 8];
  const unsigned short* Bbase = Wpack + l * 16384;
  short8 bfr[4][2];
#pragma unroll
  for (int kt = 0; kt < 4; ++kt)
#pragma unroll
    for (int nt = 0; nt < 2; ++nt)
      bfr[kt][nt] = *(const short8*)&Bbase[((kt * 128 + w * 32 + nt * 16 + nlo) * 4 + quad) * 8];

  const short8 zero8 = {0, 0, 0, 0, 0, 0, 0, 0};
  // U-GEMM A-frags for both receivers (bf16 u rows; rows 4..15 zero)
  short8 au[2][2];
#pragma unroll
  for (int ri = 0; ri < 2; ++ri)
#pragma unroll
    for (int kt = 0; kt < 2; ++kt)
      au[ri][kt] = (nlo < 4) ? *(const short8*)&sh_ub[ri][nlo][kt * 32 + quad * 8] : zero8;

#pragma unroll
  for (int ri = 0; ri < 2; ++ri) {
    // ---- Stage B: S_ri = silu(rb_ri @ Wr1) via MFMA -> sh_S ----
#pragma unroll
    for (int mtp = 0; mtp < 2; ++mtp) {
      f32x4 Cs[2][2];
#pragma unroll
      for (int mi = 0; mi < 2; ++mi)
#pragma unroll
        for (int nt = 0; nt < 2; ++nt) Cs[mi][nt] = (f32x4){0.f, 0.f, 0.f, 0.f};
#pragma unroll
      for (int mi = 0; mi < 2; ++mi) {
        int mt = mtp * 2 + mi;
        short8 afr = (quad == 0) ? *(const short8*)&sh_rbh[ri][mt * 16 + nlo][0] : zero8;
#pragma unroll
        for (int nt = 0; nt < 2; ++nt)
          Cs[mi][nt] = __builtin_amdgcn_mfma_f32_16x16x32_bf16(afr, bw[nt], Cs[mi][nt], 0, 0, 0);
      }
#pragma unroll
      for (int mi = 0; mi < 2; ++mi)
#pragma unroll
        for (int nt = 0; nt < 2; ++nt)
#pragma unroll
          for (int reg = 0; reg < 4; ++reg) {
            int s = (mtp * 2 + mi) * 16 + quad * 4 + reg;
            int c = w * 32 + nt * 16 + nlo;
            sh_S[s][c] = bf1(silu_f(Cs[mi][nt][reg]));
          }
    }
    __syncthreads();   // S_ri ready

    // ---- Main GEMM; M0 = C*h -> per-wave transposed tile (no barrier) ----
#pragma unroll
    for (int mt = 0; mt < 4; ++mt) {
      short8 afr[4];
      int s_a = mt * 16 + nlo;
#pragma unroll
      for (int kt = 0; kt < 4; ++kt)
        afr[kt] = *(const short8*)&sh_S[s_a][kt * 32 + quad * 8];
#pragma unroll
      for (int nt = 0; nt < 2; ++nt) {
        f32x4 C = {0.f, 0.f, 0.f, 0.f};
#pragma unroll
        for (int kt = 0; kt < 4; ++kt)
          C = __builtin_amdgcn_mfma_f32_16x16x32_bf16(afr[kt], bfr[kt][nt], C, 0, 0, 0);
        f32x4 m0 = C * hbv[mt][nt];               // pk-mul pairs
        u32x2 pk;
        pk.x = bf2(m0[0], m0[1]);
        pk.y = bf2(m0[2], m0[3]);
        *(u32x2*)&sh_M0T[w][nt * 16 + nlo][mt * 16 + quad * 4] = pk;  // own-wave tile
      }
    }
    // ---- U-GEMM: [a0;a1x;a1y;a1z](this wave's 32 cols) = U @ M0 ----
    {
      f32x4 Cu[2] = {{0, 0, 0, 0}, {0, 0, 0, 0}};
#pragma unroll
      for (int nt = 0; nt < 2; ++nt)
#pragma unroll
        for (int kt = 0; kt < 2; ++kt) {
          short8 bm = *(const short8*)&sh_M0T[w][nt * 16 + nlo][kt * 32 + quad * 8];
          Cu[nt] = __builtin_amdgcn_mfma_f32_16x16x32_bf16(au[ri][kt], bm, Cu[nt], 0, 0, 0);
        }
      if (quad == 0) {
#pragma unroll
        for (int nt = 0; nt < 2; ++nt) {
          size_t base = (size_t)(b * NN + r0 + ri) * HH + w * 32 + nt * 16 + nlo;
#pragma unroll
          for (int reg = 0; reg < 4; ++reg)
            apout[(l * 4 + reg) * PLANE + base] = bf1(Cu[nt][reg]);
        }
      }
    }
    if (ri == 0) __syncthreads();   // sh_S reads done before ri=1 overwrite
  }
}

// Final update + readout, 8 rows/block (grid 512), 10 MFMA GEMMs in-block.
__global__ __launch_bounds__(256) void k_update_ro(
    const unsigned short* __restrict__ apbf, const float* __restrict__ hA,
    const unsigned short* __restrict__ Wpack,
    const float* __restrict__ fs, float* __restrict__ out) {
  __shared__ __align__(16) unsigned short sh_a[8][8][136];   // [0] aliased by q later
  __shared__ __align__(16) unsigned short sh_h[8][136];
  __shared__ float red[4][8][3];
  int tid = threadIdx.x, w = tid >> 6, lane = tid & 63;
  int nlo = lane & 15, quad = lane >> 4;
  int row0 = blockIdx.x * 8;
  for (int i = tid; i < 8 * 8 * 64; i += 256) {
    int p = i >> 9, rr = (i >> 6) & 7, c2 = (i & 63) * 2;
    *(unsigned*)&sh_a[p][rr][c2] =
        *(const unsigned*)&apbf[p * PLANE + (size_t)(row0 + rr) * HH + c2];
  }
  f32x4 Ch[2];
#pragma unroll
  for (int nt = 0; nt < 2; ++nt)
#pragma unroll
    for (int reg = 0; reg < 4; ++reg)
      Ch[nt][reg] = (quad < 2)
          ? hA[(size_t)(row0 + quad * 4 + reg) * HH + w * 32 + nt * 16 + nlo] : 0.f;
  __syncthreads();
  gemm8(sh_a[0], Wpack + 2 * 16384, w, nlo, quad, Ch);   // + a0l0@Wupd0
  gemm8(sh_a[4], Wpack + 3 * 16384, w, nlo, quad, Ch);   // + a0l1@Wupd1
  f32x4 Cx[2] = {{0,0,0,0},{0,0,0,0}};
  f32x4 Cy[2] = {{0,0,0,0},{0,0,0,0}};
  f32x4 Cz[2] = {{0,0,0,0},{0,0,0,0}};
  gemm8(sh_a[1], Wpack + 4 * 16384, w, nlo, quad, Cx);
  gemm8(sh_a[5], Wpack + 5 * 16384, w, nlo, quad, Cx);
  gemm8(sh_a[2], Wpack + 4 * 16384, w, nlo, quad, Cy);
  gemm8(sh_a[6], Wpack + 5 * 16384, w, nlo, quad, Cy);
  gemm8(sh_a[3], Wpack + 4 * 16384, w, nlo, quad, Cz);
  gemm8(sh_a[7], Wpack + 5 * 16384, w, nlo, quad, Cz);
  if (quad < 2) {
#pragma unroll
    for (int nt = 0; nt < 2; ++nt)
#pragma unroll
      for (int reg = 0; reg < 4; ++reg)
        sh_h[quad * 4 + reg][w * 32 + nt * 16 + nlo] = bf1(Ch[nt][reg]);
  }
  __syncthreads();   // sh_h ready; sh_a reads done -> sh_a[0] free to alias
  unsigned short (*sh_q)[136] = sh_a[0];
  f32x4 Cq[2] = {{0,0,0,0},{0,0,0,0}};
  gemm8(sh_h, Wpack + 6 * 16384, w, nlo, quad, Cq);
  if (quad < 2) {
#pragma unroll
    for (int nt = 0; nt < 2; ++nt)
#pragma unroll
      for (int reg = 0; reg < 4; ++reg)
        sh_q[quad * 4 + reg][w * 32 + nt * 16 + nlo] = bf1(silu_f(Cq[nt][reg]));
  }
  __syncthreads();
  f32x4 Cg[2] = {{0,0,0,0},{0,0,0,0}};
  gemm8(sh_q, Wpack + 7 * 16384, w, nlo, quad, Cg);
  float pr[3][4];
#pragma unroll
  for (int d = 0; d < 3; ++d)
#pragma unroll
    for (int reg = 0; reg < 4; ++reg) pr[d][reg] = 0.f;
#pragma unroll
  for (int nt = 0; nt < 2; ++nt)
#pragma unroll
    for (int reg = 0; reg < 4; ++reg) {
      float gv = Cg[nt][reg];
      pr[0][reg] += gv * Cx[nt][reg];
      pr[1][reg] += gv * Cy[nt][reg];
      pr[2][reg] += gv * Cz[nt][reg];
    }
#pragma unroll
  for (int off = 1; off < 16; off <<= 1)
#pragma unroll
    for (int d = 0; d < 3; ++d)
#pragma unroll
      for (int reg = 0; reg < 4; ++reg)
        pr[d][reg] += __shfl_xor(pr[d][reg], off);
  if (nlo == 0 && quad < 2) {
#pragma unroll
    for (int d = 0; d < 3; ++d)
#pragma unroll
      for (int reg = 0; reg < 4; ++reg)
        red[w][quad * 4 + reg][d] = pr[d][reg];
  }
  __syncthreads();
  if (tid < 24) {
    int row = tid / 3, d = tid % 3;
    float s = red[0][row][d] + red[1][row][d] + red[2][row][d] + red[3][row][d];
    out[(size_t)(row0 + row) * 3 + d] = s * fs[0];
  }
}

extern "C" void kernel_launch(void* const* d_in, const int* in_sizes, int n_in,
                              void* d_out, int out_size, void* d_ws, size_t ws_size,
                              hipStream_t stream) {
  const float* pos  = (const float*)d_in[0];
  const int*   z    = (const int*)d_in[1];
  const float* gf   = (const float*)d_in[2];
  const float* emb  = (const float*)d_in[3];
  const float* Wt   = (const float*)d_in[4];
  const float* Wr1  = (const float*)d_in[5];
  const float* Wr2  = (const float*)d_in[6];
  const float* Wupd = (const float*)d_in[7];
  const float* Wmix = (const float*)d_in[8];
  const float* Wg1  = (const float*)d_in[9];
  const float* Wg2  = (const float*)d_in[10];
  const float* fs   = (const float*)d_in[11];
  float* out = (float*)d_out;

  float* ws = (float*)d_ws;
  float* hA = ws;                                         // 2 MB
  unsigned short* apbf = (unsigned short*)(ws + PLANE);   // 8 bf16 planes = 8 MB
  unsigned short* Wpack = (unsigned short*)(ws + 5 * PLANE);  // 272 KB

  k_init<<<dim3(256), dim3(256), 0, stream>>>(emb, z, gf, Wt, Wr1, Wr2, Wupd,
                                              Wmix, Wg1, Wg2, hA, Wpack);
  k_layer<<<dim3(BB * 32), dim3(256), 0, stream>>>(pos, hA, apbf, apbf, Wpack, 0);
  k_layer<<<dim3(BB * 32), dim3(256), 0, stream>>>(pos, hA, apbf, apbf, Wpack, 1);
  k_update_ro<<<dim3(512), dim3(256), 0, stream>>>(apbf, hA, Wpack, fs, out);
}